// Round 19
// baseline (61.283 us; speedup 1.0000x reference)
//
#include <hip/hip_runtime.h>
#include <hip/hip_bf16.h>

#define NN 2048
#define NH 12
#define HD 32
#define CALL 384   // NH*HD == OUT
#define NJS 8      // j-splits for attn

typedef float f32x16 __attribute__((ext_vector_type(16)));
typedef _Float16 f16x4 __attribute__((ext_vector_type(4)));
typedef __fp16 fp16x2 __attribute__((ext_vector_type(2)));

static __device__ __forceinline__ f32x16 mfma8f16(f16x4 a, f16x4 b, f32x16 c) {
    return __builtin_amdgcn_mfma_f32_32x32x8f16(a, b, c, 0, 0, 0);
}
static __device__ __forceinline__ f16x4 u2f(uint2 u) {
    union { uint2 u2; f16x4 f; } c; c.u2 = u; return c.f;
}
// zero-VGPR async global->LDS copy, 16B per lane (dest = wave base + lane*16)
static __device__ __forceinline__ void gload16(const void* gp, void* lp) {
    __builtin_amdgcn_global_load_lds(
        (const __attribute__((address_space(1))) unsigned int*)gp,
        (__attribute__((address_space(3))) unsigned int*)lp, 16, 0, 0);
}

// ---------------------------------------------------------------------------
// gemm01 (R17 best): fused first two GEMMs, K-SPLIT 8-wave blocks + T14.
// z=0: h = x W^T -> outT (f16 [384][2048]) + FUSED srcdst
// z=1: res = x resW^T -> outF (f32 [2048][384]) + bias
// ---------------------------------------------------------------------------
__global__ __launch_bounds__(512) void gemm01(
    const float* __restrict__ A, const float* __restrict__ B0,
    const float* __restrict__ B1, const float* __restrict__ bias1,
    const float* __restrict__ attn_src, const float* __restrict__ attn_dst,
    _Float16* __restrict__ outT, float* __restrict__ outF,
    float* __restrict__ asrc, float* __restrict__ adstT)
{
    __shared__ __align__(16) char smem[17408];
    _Float16 (*As)[68] = (_Float16(*)[68])(smem);
    _Float16 (*Bs)[68] = (_Float16(*)[68])(smem + 8704);
    float* red = (float*)smem;

    const int t = threadIdx.x;
    const int w = t >> 6, l = t & 63, g = l >> 5, il = l & 31;
    const int q = w & 3, kg = w >> 2;
    const int m0 = blockIdx.x * 64, n0 = blockIdx.y * 64;
    const int mode = blockIdx.z;
    const float* B = mode ? B1 : B0;
    const int wr = (q >> 1) * 32, wc = (q & 1) * 32;
    const int ti = t >> 3, seg = t & 7;
    const int Kdim = 256;

    const float* Abase = A + (size_t)(m0 + ti) * Kdim + seg * 8;
    const float* Bbase = B + (size_t)(n0 + ti) * Kdim + seg * 8;

    f32x16 acc;
#pragma unroll
    for (int r = 0; r < 16; ++r) acc[r] = 0.f;

    float4 av0 = *reinterpret_cast<const float4*>(Abase);
    float4 av1 = *reinterpret_cast<const float4*>(Abase + 4);
    float4 bv0 = *reinterpret_cast<const float4*>(Bbase);
    float4 bv1 = *reinterpret_cast<const float4*>(Bbase + 4);

#pragma unroll 1
    for (int ss = 0; ss < 4; ++ss) {
        __syncthreads();
        {
            f16x4 lo = {(_Float16)av0.x, (_Float16)av0.y, (_Float16)av0.z, (_Float16)av0.w};
            f16x4 hi = {(_Float16)av1.x, (_Float16)av1.y, (_Float16)av1.z, (_Float16)av1.w};
            *reinterpret_cast<f16x4*>(&As[ti][seg * 8])     = lo;
            *reinterpret_cast<f16x4*>(&As[ti][seg * 8 + 4]) = hi;
            f16x4 lo2 = {(_Float16)bv0.x, (_Float16)bv0.y, (_Float16)bv0.z, (_Float16)bv0.w};
            f16x4 hi2 = {(_Float16)bv1.x, (_Float16)bv1.y, (_Float16)bv1.z, (_Float16)bv1.w};
            *reinterpret_cast<f16x4*>(&Bs[ti][seg * 8])     = lo2;
            *reinterpret_cast<f16x4*>(&Bs[ti][seg * 8 + 4]) = hi2;
        }
        __syncthreads();
        if (ss < 3) {
            const int kk = (ss + 1) * 64;
            av0 = *reinterpret_cast<const float4*>(Abase + kk);
            av1 = *reinterpret_cast<const float4*>(Abase + kk + 4);
            bv0 = *reinterpret_cast<const float4*>(Bbase + kk);
            bv1 = *reinterpret_cast<const float4*>(Bbase + kk + 4);
        }
#pragma unroll
        for (int kc = 0; kc < 4; ++kc) {
            f16x4 af = *reinterpret_cast<const f16x4*>(&As[wr + il][kg * 32 + kc * 8 + 4 * g]);
            f16x4 bf = *reinterpret_cast<const f16x4*>(&Bs[wc + il][kg * 32 + kc * 8 + 4 * g]);
            acc = mfma8f16(af, bf, acc);
        }
    }

    __syncthreads();
    if (kg == 1) {
#pragma unroll
        for (int r = 0; r < 16; ++r) red[(q * 16 + r) * 64 + l] = acc[r];
    }
    __syncthreads();
    if (kg != 0) return;
#pragma unroll
    for (int r = 0; r < 16; ++r) acc[r] += red[(q * 16 + r) * 64 + l];

    const int colg = n0 + wc + il;
    if (mode == 0) {
#pragma unroll
        for (int p = 0; p < 4; ++p) {
            const int row = m0 + wr + 8 * p + 4 * g;
            f16x4 v;
#pragma unroll
            for (int r = 0; r < 4; ++r) v[r] = (_Float16)acc[4 * p + r];
            *reinterpret_cast<f16x4*>(&outT[(size_t)colg * NN + row]) = v;
        }
        const int hstar = colg >> 5;
        const float sv = attn_src[hstar * HD + il];
        const float dv = attn_dst[hstar * HD + il];
        float ps[16], pd[16];
#pragma unroll
        for (int r = 0; r < 16; ++r) { ps[r] = acc[r] * sv; pd[r] = acc[r] * dv; }
#pragma unroll
        for (int m = 1; m <= 16; m <<= 1) {
#pragma unroll
            for (int r = 0; r < 16; ++r) {
                ps[r] += __shfl_xor(ps[r], m);
                pd[r] += __shfl_xor(pd[r], m);
            }
        }
        if (il == 0) {
#pragma unroll
            for (int r = 0; r < 16; ++r) {
                const int row = m0 + wr + (r & 3) + 8 * (r >> 2) + 4 * g;
                asrc[row * NH + hstar] = ps[r];
                adstT[(size_t)hstar * NN + row] = pd[r] * 1.44269504089f;
            }
        }
    } else {
        const float bs = bias1[colg];
#pragma unroll
        for (int r = 0; r < 16; ++r) {
            const int row = m0 + wr + (r & 3) + 8 * (r >> 2) + 4 * g;
            outF[(size_t)row * CALL + colg] = acc[r] + bs;
        }
    }
}

// ---------------------------------------------------------------------------
// gemm2 (R17 best): final GEMM (K=384), K-SPLIT + T14. + bias + exact GELU.
// ---------------------------------------------------------------------------
__global__ __launch_bounds__(512) void gemm2(
    const _Float16* __restrict__ A16, const float* __restrict__ B,
    const float* __restrict__ bias, float* __restrict__ outF)
{
    __shared__ __align__(16) char smem[17408];
    _Float16 (*As)[68] = (_Float16(*)[68])(smem);
    _Float16 (*Bs)[68] = (_Float16(*)[68])(smem + 8704);
    float* red = (float*)smem;

    const int t = threadIdx.x;
    const int w = t >> 6, l = t & 63, g = l >> 5, il = l & 31;
    const int q = w & 3, kg = w >> 2;
    const int m0 = blockIdx.x * 64, n0 = blockIdx.y * 64;
    const int wr = (q >> 1) * 32, wc = (q & 1) * 32;
    const int ti = t >> 3, seg = t & 7;
    const int Kdim = 384;

    const _Float16* Abase = A16 + (size_t)(m0 + ti) * Kdim + seg * 8;
    const float*    Bbase = B   + (size_t)(n0 + ti) * Kdim + seg * 8;

    f32x16 acc;
#pragma unroll
    for (int r = 0; r < 16; ++r) acc[r] = 0.f;

    uint4  av = *reinterpret_cast<const uint4*>(Abase);
    float4 bv0 = *reinterpret_cast<const float4*>(Bbase);
    float4 bv1 = *reinterpret_cast<const float4*>(Bbase + 4);

#pragma unroll 1
    for (int ss = 0; ss < 6; ++ss) {
        __syncthreads();
        {
            *reinterpret_cast<uint2*>(&As[ti][seg * 8])     = make_uint2(av.x, av.y);
            *reinterpret_cast<uint2*>(&As[ti][seg * 8 + 4]) = make_uint2(av.z, av.w);
            f16x4 lo = {(_Float16)bv0.x, (_Float16)bv0.y, (_Float16)bv0.z, (_Float16)bv0.w};
            f16x4 hi = {(_Float16)bv1.x, (_Float16)bv1.y, (_Float16)bv1.z, (_Float16)bv1.w};
            *reinterpret_cast<f16x4*>(&Bs[ti][seg * 8])     = lo;
            *reinterpret_cast<f16x4*>(&Bs[ti][seg * 8 + 4]) = hi;
        }
        __syncthreads();
        if (ss < 5) {
            const int kk = (ss + 1) * 64;
            av  = *reinterpret_cast<const uint4*>(Abase + kk);
            bv0 = *reinterpret_cast<const float4*>(Bbase + kk);
            bv1 = *reinterpret_cast<const float4*>(Bbase + kk + 4);
        }
#pragma unroll
        for (int kc = 0; kc < 4; ++kc) {
            f16x4 af = *reinterpret_cast<const f16x4*>(&As[wr + il][kg * 32 + kc * 8 + 4 * g]);
            f16x4 bf = *reinterpret_cast<const f16x4*>(&Bs[wc + il][kg * 32 + kc * 8 + 4 * g]);
            acc = mfma8f16(af, bf, acc);
        }
    }

    __syncthreads();
    if (kg == 1) {
#pragma unroll
        for (int r = 0; r < 16; ++r) red[(q * 16 + r) * 64 + l] = acc[r];
    }
    __syncthreads();
    if (kg != 0) return;
#pragma unroll
    for (int r = 0; r < 16; ++r) acc[r] += red[(q * 16 + r) * 64 + l];

    const int colg = n0 + wc + il;
    const float bs = bias[colg];
#pragma unroll
    for (int r = 0; r < 16; ++r) {
        const int row = m0 + wr + (r & 3) + 8 * (r >> 2) + 4 * g;
        float vv = acc[r] + bs;
        vv = 0.5f * vv * (1.0f + erff(vv * 0.70710678118f));
        outF[(size_t)row * CALL + colg] = vv;
    }
}

// ---------------------------------------------------------------------------
// attn16: BLOCK-COOPERATIVE staging. Block = 32-row band x ALL 12 heads,
// 768 thr = 12 waves (wave = head, acc 16 regs). Grid 64 bands x 8 j-splits
// = 512 blocks = 2/CU = 6 waves/SIMD. Per 32-j tile the block DMA-stages
// adj[8G][32][16B] (4KB) + hT[4P][512][16B] (32KB, slot-major: lane reads
// are 16B-contiguous across lanes = conflict-free, DMA sources are 16B
// contiguous per lane = coalesced) + adst[12][32]f32 (2KB), double-buffered,
// ONE barrier + own-vmcnt per tile. ZERO per-wave global loads in the loop.
// Each wave owns a disjoint 32x32 output tile -> partials straight to
// global (numerP/denomP), no cross-wave reduce. combine() finishes.
// ---------------------------------------------------------------------------
#define SLICE 38912   // adj 4096 | hT 32768 | adst 2048
__global__ __launch_bounds__(768, 6) void attn16(
    const float* __restrict__ adj, const _Float16* __restrict__ hT,
    const float* __restrict__ asrc, const float* __restrict__ adstT,
    const float* __restrict__ eW, const float* __restrict__ eb,
    float* __restrict__ numerP, float* __restrict__ denomP)
{
    __shared__ __align__(16) char smem[2 * SLICE];
    const int t = threadIdx.x;
    const int w = t >> 6, l = t & 63, g = l >> 5, il = l & 31;
    const int band = blockIdx.x, js = blockIdx.y;
    const int i0 = band * 32, h = w;
    const int jbase = js * 256;

    // stage one 32-j tile into buf (per-wave DMA responsibilities)
    auto STAGE = [&](char* buf, int jb) {
        // hT: 24 issues, wave w does p=2w,2w+1; layout [P][c<512][16B]
#pragma unroll
        for (int e = 0; e < 2; ++e) {
            const int p = 2 * w + e;
            const int P = p / 6, qq = p - P * 6;
            gload16(hT + (size_t)(qq * 64 + l) * NN + jb + P * 8,
                    buf + 4096 + P * 8192 + qq * 1024);
        }
        // adj: 4 issues (waves 0-3); layout [G][r][16B]
        if (w < 4)
            gload16(adj + (size_t)(i0 + (l & 31)) * NN + jb + (2 * w + (l >> 5)) * 4,
                    buf + w * 1024);
        // adst: 2 issues (waves 4,5); layout [h][32]f32 (+512B pad)
        if (w == 4 || w == 5) {
            const int e2 = w - 4;
            const int hsrc = (e2 == 0) ? (l >> 3) : (8 + ((l >> 3) & 3));
            gload16(adstT + (size_t)hsrc * NN + jb + (l & 7) * 4,
                    buf + 36864 + e2 * 1024);
        }
    };

    const float LOG2E = 1.44269504089f;
    const float base = (asrc[(size_t)(i0 + il) * NH + h] + eb[h]) * LOG2E;
    const float eWr = eW[h] * LOG2E;

    f32x16 acc;
#pragma unroll
    for (int r = 0; r < 16; ++r) acc[r] = 0.f;
    float4 dsum = make_float4(0.f, 0.f, 0.f, 0.f);

    char* buf0 = smem;
    char* buf1 = smem + SLICE;

    STAGE(buf0, jbase);
    asm volatile("s_waitcnt vmcnt(0)" ::: "memory");
    __syncthreads();

#pragma unroll 1
    for (int tl = 0; tl < 8; ++tl) {
        char* buf  = (tl & 1) ? buf1 : buf0;
        char* nbuf = (tl & 1) ? buf0 : buf1;
        if (tl < 7) STAGE(nbuf, jbase + (tl + 1) * 32);

        char* adjB = buf;
        char* hTB  = buf + 4096;
        const float* adstB = (const float*)(buf + 36864);
#pragma unroll
        for (int kp = 0; kp < 2; ++kp) {
            const uint4 hv = *reinterpret_cast<const uint4*>(
                hTB + (2 * g + kp) * 8192 + (h * 32 + il) * 16);
#pragma unroll
            for (int ks2 = 0; ks2 < 2; ++ks2) {
                const int ks = 2 * kp + ks2;
                const int G = 4 * g + ks;
                const float4 aj = *reinterpret_cast<const float4*>(adjB + G * 512 + il * 16);
                const float4 ad = *reinterpret_cast<const float4*>(adstB + h * 32 + G * 4);
                float e0, e1, e2, e3;
#pragma unroll
                for (int jj = 0; jj < 4; ++jj) {
                    const float ajv = (&aj.x)[jj];
                    float tt = fmaf(ajv, eWr, base + (&ad.x)[jj]);
                    tt = fmaxf(tt, 0.2f * tt);
                    const float ee = ajv > 0.f ? __builtin_amdgcn_exp2f(tt) : 0.f;
                    (&dsum.x)[jj] += ee;
                    (jj == 0 ? e0 : jj == 1 ? e1 : jj == 2 ? e2 : e3) = ee;
                }
                union { fp16x2 h2[2]; f16x4 h4; } u;
                u.h2[0] = __builtin_amdgcn_cvt_pkrtz(e0, e1);
                u.h2[1] = __builtin_amdgcn_cvt_pkrtz(e2, e3);
                const uint2 hu = ks2 ? make_uint2(hv.z, hv.w) : make_uint2(hv.x, hv.y);
                acc = mfma8f16(u.h4, u2f(hu), acc);
            }
        }
        asm volatile("s_waitcnt vmcnt(0)" ::: "memory");
        __syncthreads();
    }

    // epilogue: wave owns disjoint 32x32 tile -> straight to global partials
    float dt = (dsum.x + dsum.y) + (dsum.z + dsum.w);
    dt += __shfl_xor(dt, 32);
    if (l < 32)
        denomP[(size_t)js * NN * NH + (size_t)(i0 + l) * NH + h] = dt;
#pragma unroll
    for (int r = 0; r < 16; ++r) {
        const int row = (r & 3) + 8 * (r >> 2) + 4 * g;
        numerP[(size_t)js * NN * CALL + (size_t)(i0 + row) * CALL + h * 32 + il] = acc[r];
    }
}

// ---------------------------------------------------------------------------
// combine: hsum = (sum_js numerP) / (sum_js denomP) + res -> f16
// grid 1024 x block (96,2): i = bx*2 + ty, c = tx*4. No divisions.
// ---------------------------------------------------------------------------
__global__ __launch_bounds__(192) void combine(
    const float* __restrict__ numerP, const float* __restrict__ denomP,
    const float* __restrict__ res, _Float16* __restrict__ hsum)
{
    const int i = blockIdx.x * 2 + threadIdx.y;
    const int c = threadIdx.x * 4;
    const int h = c >> 5;
    float4 s = make_float4(0.f, 0.f, 0.f, 0.f);
    float d = 0.f;
#pragma unroll
    for (int js = 0; js < NJS; ++js) {
        const float4 v = *reinterpret_cast<const float4*>(
            numerP + (size_t)js * NN * CALL + (size_t)i * CALL + c);
        s.x += v.x; s.y += v.y; s.z += v.z; s.w += v.w;
        d += denomP[(size_t)js * NN * NH + (size_t)i * NH + h];
    }
    const float4 rv = *reinterpret_cast<const float4*>(res + (size_t)i * CALL + c);
    const float inv = 1.0f / d;
    f16x4 o = {(_Float16)(s.x * inv + rv.x), (_Float16)(s.y * inv + rv.y),
               (_Float16)(s.z * inv + rv.z), (_Float16)(s.w * inv + rv.w)};
    *reinterpret_cast<f16x4*>(hsum + (size_t)i * CALL + c) = o;
}

extern "C" void kernel_launch(void* const* d_in, const int* in_sizes, int n_in,
                              void* d_out, int out_size, void* d_ws, size_t ws_size,
                              hipStream_t stream)
{
    const float* x        = (const float*)d_in[0];
    const float* adj      = (const float*)d_in[1];
    const float* W        = (const float*)d_in[2];
    const float* attn_src = (const float*)d_in[3];
    const float* attn_dst = (const float*)d_in[4];
    const float* edge_W   = (const float*)d_in[5];
    const float* edge_b   = (const float*)d_in[6];
    const float* res_W    = (const float*)d_in[7];
    const float* res_b    = (const float*)d_in[8];
    const float* fus_W    = (const float*)d_in[9];
    const float* fus_b    = (const float*)d_in[10];
    float* out = (float*)d_out;

    char* ws = (char*)d_ws;
    size_t off = 0;
    auto alloc = [&](size_t bytes) { void* p = ws + off; off = (off + bytes + 255) & ~(size_t)255; return p; };
    _Float16* hT     = (_Float16*)alloc((size_t)CALL * NN * 2);
    float*    res    = (float*)alloc((size_t)NN * CALL * 4);
    float*    asrc   = (float*)alloc((size_t)NN * NH * 4);
    float*    adstT  = (float*)alloc((size_t)NH * NN * 4);
    _Float16* hsum   = (_Float16*)alloc((size_t)NN * CALL * 2);
    float*    numerP = (float*)alloc((size_t)NJS * NN * CALL * 4);
    float*    denomP = (float*)alloc((size_t)NJS * NN * NH * 4);
    (void)ws_size;

    gemm01<<<dim3(32, 6, 2), dim3(512), 0, stream>>>(x, W, res_W, res_b, attn_src, attn_dst, hT, res, asrc, adstT);
    attn16<<<dim3(64, NJS), dim3(768), 0, stream>>>(adj, hT, asrc, adstT, edge_W, edge_b, numerP, denomP);
    combine<<<1024, dim3(96, 2), 0, stream>>>(numerP, denomP, res, hsum);
    gemm2<<<dim3(32, 6), dim3(512), 0, stream>>>(hsum, fus_W, fus_b, out);
}

// Round 20
// 49.472 us; speedup vs baseline: 1.2387x; 1.2387x over previous
//
#include <hip/hip_runtime.h>
#include <hip/hip_bf16.h>

#define NN 2048
#define NH 12
#define HD 32
#define CALL 384   // NH*HD == OUT

typedef float f32x16 __attribute__((ext_vector_type(16)));
typedef _Float16 f16x4 __attribute__((ext_vector_type(4)));
typedef __fp16 fp16x2 __attribute__((ext_vector_type(2)));

static __device__ __forceinline__ f32x16 mfma8f16(f16x4 a, f16x4 b, f32x16 c) {
    return __builtin_amdgcn_mfma_f32_32x32x8f16(a, b, c, 0, 0, 0);
}
static __device__ __forceinline__ f16x4 u2f(uint2 u) {
    union { uint2 u2; f16x4 f; } c; c.u2 = u; return c.f;
}
// zero-VGPR async global->LDS copy, 16B per lane (dest = wave base + lane*16)
static __device__ __forceinline__ void gload16(const void* gp, void* lp) {
    __builtin_amdgcn_global_load_lds(
        (const __attribute__((address_space(1))) unsigned int*)gp,
        (__attribute__((address_space(3))) unsigned int*)lp, 16, 0, 0);
}

// ---------------------------------------------------------------------------
// gemm01 (R17 best): fused first two GEMMs, K-SPLIT 8-wave blocks + T14.
// z=0: h = x W^T -> outT (f16 [384][2048]) + FUSED srcdst
// z=1: res = x resW^T -> outF (f32 [2048][384]) + bias
// ---------------------------------------------------------------------------
__global__ __launch_bounds__(512) void gemm01(
    const float* __restrict__ A, const float* __restrict__ B0,
    const float* __restrict__ B1, const float* __restrict__ bias1,
    const float* __restrict__ attn_src, const float* __restrict__ attn_dst,
    _Float16* __restrict__ outT, float* __restrict__ outF,
    float* __restrict__ asrc, float* __restrict__ adstT)
{
    __shared__ __align__(16) char smem[17408];
    _Float16 (*As)[68] = (_Float16(*)[68])(smem);
    _Float16 (*Bs)[68] = (_Float16(*)[68])(smem + 8704);
    float* red = (float*)smem;

    const int t = threadIdx.x;
    const int w = t >> 6, l = t & 63, g = l >> 5, il = l & 31;
    const int q = w & 3, kg = w >> 2;
    const int m0 = blockIdx.x * 64, n0 = blockIdx.y * 64;
    const int mode = blockIdx.z;
    const float* B = mode ? B1 : B0;
    const int wr = (q >> 1) * 32, wc = (q & 1) * 32;
    const int ti = t >> 3, seg = t & 7;
    const int Kdim = 256;

    const float* Abase = A + (size_t)(m0 + ti) * Kdim + seg * 8;
    const float* Bbase = B + (size_t)(n0 + ti) * Kdim + seg * 8;

    f32x16 acc;
#pragma unroll
    for (int r = 0; r < 16; ++r) acc[r] = 0.f;

    float4 av0 = *reinterpret_cast<const float4*>(Abase);
    float4 av1 = *reinterpret_cast<const float4*>(Abase + 4);
    float4 bv0 = *reinterpret_cast<const float4*>(Bbase);
    float4 bv1 = *reinterpret_cast<const float4*>(Bbase + 4);

#pragma unroll 1
    for (int ss = 0; ss < 4; ++ss) {
        __syncthreads();
        {
            f16x4 lo = {(_Float16)av0.x, (_Float16)av0.y, (_Float16)av0.z, (_Float16)av0.w};
            f16x4 hi = {(_Float16)av1.x, (_Float16)av1.y, (_Float16)av1.z, (_Float16)av1.w};
            *reinterpret_cast<f16x4*>(&As[ti][seg * 8])     = lo;
            *reinterpret_cast<f16x4*>(&As[ti][seg * 8 + 4]) = hi;
            f16x4 lo2 = {(_Float16)bv0.x, (_Float16)bv0.y, (_Float16)bv0.z, (_Float16)bv0.w};
            f16x4 hi2 = {(_Float16)bv1.x, (_Float16)bv1.y, (_Float16)bv1.z, (_Float16)bv1.w};
            *reinterpret_cast<f16x4*>(&Bs[ti][seg * 8])     = lo2;
            *reinterpret_cast<f16x4*>(&Bs[ti][seg * 8 + 4]) = hi2;
        }
        __syncthreads();
        if (ss < 3) {
            const int kk = (ss + 1) * 64;
            av0 = *reinterpret_cast<const float4*>(Abase + kk);
            av1 = *reinterpret_cast<const float4*>(Abase + kk + 4);
            bv0 = *reinterpret_cast<const float4*>(Bbase + kk);
            bv1 = *reinterpret_cast<const float4*>(Bbase + kk + 4);
        }
#pragma unroll
        for (int kc = 0; kc < 4; ++kc) {
            f16x4 af = *reinterpret_cast<const f16x4*>(&As[wr + il][kg * 32 + kc * 8 + 4 * g]);
            f16x4 bf = *reinterpret_cast<const f16x4*>(&Bs[wc + il][kg * 32 + kc * 8 + 4 * g]);
            acc = mfma8f16(af, bf, acc);
        }
    }

    __syncthreads();
    if (kg == 1) {
#pragma unroll
        for (int r = 0; r < 16; ++r) red[(q * 16 + r) * 64 + l] = acc[r];
    }
    __syncthreads();
    if (kg != 0) return;
#pragma unroll
    for (int r = 0; r < 16; ++r) acc[r] += red[(q * 16 + r) * 64 + l];

    const int colg = n0 + wc + il;
    if (mode == 0) {
#pragma unroll
        for (int p = 0; p < 4; ++p) {
            const int row = m0 + wr + 8 * p + 4 * g;
            f16x4 v;
#pragma unroll
            for (int r = 0; r < 4; ++r) v[r] = (_Float16)acc[4 * p + r];
            *reinterpret_cast<f16x4*>(&outT[(size_t)colg * NN + row]) = v;
        }
        const int hstar = colg >> 5;
        const float sv = attn_src[hstar * HD + il];
        const float dv = attn_dst[hstar * HD + il];
        float ps[16], pd[16];
#pragma unroll
        for (int r = 0; r < 16; ++r) { ps[r] = acc[r] * sv; pd[r] = acc[r] * dv; }
#pragma unroll
        for (int m = 1; m <= 16; m <<= 1) {
#pragma unroll
            for (int r = 0; r < 16; ++r) {
                ps[r] += __shfl_xor(ps[r], m);
                pd[r] += __shfl_xor(pd[r], m);
            }
        }
        if (il == 0) {
#pragma unroll
            for (int r = 0; r < 16; ++r) {
                const int row = m0 + wr + (r & 3) + 8 * (r >> 2) + 4 * g;
                asrc[row * NH + hstar] = ps[r];
                adstT[(size_t)hstar * NN + row] = pd[r] * 1.44269504089f;
            }
        }
    } else {
        const float bs = bias1[colg];
#pragma unroll
        for (int r = 0; r < 16; ++r) {
            const int row = m0 + wr + (r & 3) + 8 * (r >> 2) + 4 * g;
            outF[(size_t)row * CALL + colg] = acc[r] + bs;
        }
    }
}

// ---------------------------------------------------------------------------
// gemm2 (R17 best): final GEMM (K=384), K-SPLIT + T14. + bias + exact GELU.
// ---------------------------------------------------------------------------
__global__ __launch_bounds__(512) void gemm2(
    const _Float16* __restrict__ A16, const float* __restrict__ B,
    const float* __restrict__ bias, float* __restrict__ outF)
{
    __shared__ __align__(16) char smem[17408];
    _Float16 (*As)[68] = (_Float16(*)[68])(smem);
    _Float16 (*Bs)[68] = (_Float16(*)[68])(smem + 8704);
    float* red = (float*)smem;

    const int t = threadIdx.x;
    const int w = t >> 6, l = t & 63, g = l >> 5, il = l & 31;
    const int q = w & 3, kg = w >> 2;
    const int m0 = blockIdx.x * 64, n0 = blockIdx.y * 64;
    const int wr = (q >> 1) * 32, wc = (q & 1) * 32;
    const int ti = t >> 3, seg = t & 7;
    const int Kdim = 384;

    const _Float16* Abase = A16 + (size_t)(m0 + ti) * Kdim + seg * 8;
    const float*    Bbase = B   + (size_t)(n0 + ti) * Kdim + seg * 8;

    f32x16 acc;
#pragma unroll
    for (int r = 0; r < 16; ++r) acc[r] = 0.f;

    uint4  av = *reinterpret_cast<const uint4*>(Abase);
    float4 bv0 = *reinterpret_cast<const float4*>(Bbase);
    float4 bv1 = *reinterpret_cast<const float4*>(Bbase + 4);

#pragma unroll 1
    for (int ss = 0; ss < 6; ++ss) {
        __syncthreads();
        {
            *reinterpret_cast<uint2*>(&As[ti][seg * 8])     = make_uint2(av.x, av.y);
            *reinterpret_cast<uint2*>(&As[ti][seg * 8 + 4]) = make_uint2(av.z, av.w);
            f16x4 lo = {(_Float16)bv0.x, (_Float16)bv0.y, (_Float16)bv0.z, (_Float16)bv0.w};
            f16x4 hi = {(_Float16)bv1.x, (_Float16)bv1.y, (_Float16)bv1.z, (_Float16)bv1.w};
            *reinterpret_cast<f16x4*>(&Bs[ti][seg * 8])     = lo;
            *reinterpret_cast<f16x4*>(&Bs[ti][seg * 8 + 4]) = hi;
        }
        __syncthreads();
        if (ss < 5) {
            const int kk = (ss + 1) * 64;
            av  = *reinterpret_cast<const uint4*>(Abase + kk);
            bv0 = *reinterpret_cast<const float4*>(Bbase + kk);
            bv1 = *reinterpret_cast<const float4*>(Bbase + kk + 4);
        }
#pragma unroll
        for (int kc = 0; kc < 4; ++kc) {
            f16x4 af = *reinterpret_cast<const f16x4*>(&As[wr + il][kg * 32 + kc * 8 + 4 * g]);
            f16x4 bf = *reinterpret_cast<const f16x4*>(&Bs[wc + il][kg * 32 + kc * 8 + 4 * g]);
            acc = mfma8f16(af, bf, acc);
        }
    }

    __syncthreads();
    if (kg == 1) {
#pragma unroll
        for (int r = 0; r < 16; ++r) red[(q * 16 + r) * 64 + l] = acc[r];
    }
    __syncthreads();
    if (kg != 0) return;
#pragma unroll
    for (int r = 0; r < 16; ++r) acc[r] += red[(q * 16 + r) * 64 + l];

    const int colg = n0 + wc + il;
    const float bs = bias[colg];
#pragma unroll
    for (int r = 0; r < 16; ++r) {
        const int row = m0 + wr + (r & 3) + 8 * (r >> 2) + 4 * g;
        float vv = acc[r] + bs;
        vv = 0.5f * vv * (1.0f + erff(vv * 0.70710678118f));
        outF[(size_t)row * CALL + colg] = vv;
    }
}

// ---------------------------------------------------------------------------
// attn17 = attn13 (R15/R17 best) + T5 s_setprio(1) around the score+MFMA
// cluster (waves here are barrier-free/desynced -- the regime where m191
// measured +4-7%) + rcp-based epilogue division.
// ---------------------------------------------------------------------------
__global__ __launch_bounds__(1024, 4) void attn17(
    const float* __restrict__ adj, const _Float16* __restrict__ hT,
    const float* __restrict__ asrc, const float* __restrict__ adstT,
    const float* __restrict__ eW, const float* __restrict__ eb,
    const float* __restrict__ res, _Float16* __restrict__ hsum)
{
    // per-wave slice at w*5632: adj_buf 4096B (4 issues x 64 lanes x 16B) | adst 1536B
    // epilogue overlay: red[4][3][16][64] f32 (49152B) at 0 | dsum_s[16][3][32] at 49152
    __shared__ __align__(16) char smem[90112];
    const int t = threadIdx.x;
    const int w = t >> 6, l = t & 63, g = l >> 5, il = l & 31;
    const int band = blockIdx.x & 63, hg = blockIdx.x >> 6;
    const int i0 = band * 32, h0 = hg * 3, c0 = hg * 96;

    char* slice   = smem + w * 5632;
    char* adjb    = slice;                       // 4 KB adj tile buffer
    float* adst_s = (float*)(slice + 4096);
    float* red    = (float*)smem;
    float* dsum_s = (float*)(smem + 49152);

    const float LOG2E = 1.44269504089f;
    const int jbase = w * 128;
    const float* abase = adj + (size_t)(i0 + il) * NN + jbase + 16 * g;  // per-lane global

    // issue tile-0 adj prefetch immediately (latency overlaps prologue)
#pragma unroll
    for (int p = 0; p < 4; ++p)
        gload16(abase + 4 * p, adjb + p * 1024);

    float base_h[3], eWr[3];
#pragma unroll
    for (int hh = 0; hh < 3; ++hh) {
        base_h[hh] = (asrc[(size_t)(i0 + il) * NH + h0 + hh] + eb[h0 + hh]) * LOG2E;
        eWr[hh] = eW[h0 + hh] * LOG2E;
    }
#pragma unroll
    for (int p = 0; p < 6; ++p) {
        const int idx = p * 64 + l;
        adst_s[idx] = adstT[(size_t)(h0 + (idx >> 7)) * NN + jbase + (idx & 127)];
    }

    f32x16 acc[3];
#pragma unroll
    for (int hh = 0; hh < 3; ++hh)
#pragma unroll
        for (int r = 0; r < 16; ++r) acc[hh][r] = 0.f;
    float4 dsumv[3];
#pragma unroll
    for (int hh = 0; hh < 3; ++hh) dsumv[hh] = make_float4(0.f, 0.f, 0.f, 0.f);

    const _Float16* hbase = hT + (size_t)(c0 + il) * NN + jbase + 16 * g;

#pragma unroll 1
    for (int tl = 0; tl < 4; ++tl) {
        const int jo = tl * 32;
        // adj(tl) has landed in LDS once all outstanding vmem (only the
        // prefetch gloads; hT loads of tl-1 were drained by their uses) done.
        asm volatile("s_waitcnt vmcnt(0)" ::: "memory");
        const float4 aj0 = *reinterpret_cast<const float4*>(adjb + 0 * 1024 + l * 16);
        const float4 aj1 = *reinterpret_cast<const float4*>(adjb + 1 * 1024 + l * 16);
        const float4 aj2 = *reinterpret_cast<const float4*>(adjb + 2 * 1024 + l * 16);
        const float4 aj3 = *reinterpret_cast<const float4*>(adjb + 3 * 1024 + l * 16);
        // drain ds_reads, then reuse the buffer for tile tl+1 (full-tile distance)
        asm volatile("s_waitcnt lgkmcnt(0)" ::: "memory");
        if (tl < 3) {
#pragma unroll
            for (int p = 0; p < 4; ++p)
                gload16(abase + jo + 32 + 4 * p, adjb + p * 1024);
        }
        __builtin_amdgcn_s_setprio(1);
#pragma unroll
        for (int hh = 0; hh < 3; ++hh) {
            const _Float16* hp = hbase + (size_t)(hh * 32) * NN + jo;
            const uint4 hA = *reinterpret_cast<const uint4*>(hp);      // j [16g, 16g+8)
            const uint4 hB = *reinterpret_cast<const uint4*>(hp + 8);  // j [16g+8, 16g+16)
#pragma unroll
            for (int ks = 0; ks < 4; ++ks) {
                const float4 a4 = (ks == 0) ? aj0 : (ks == 1) ? aj1 : (ks == 2) ? aj2 : aj3;
                const float4 ad = *reinterpret_cast<const float4*>(
                    &adst_s[hh * 128 + jo + 16 * g + 4 * ks]);
                float e0, e1, e2, e3;
#pragma unroll
                for (int jj = 0; jj < 4; ++jj) {
                    const float ajv = (&a4.x)[jj];
                    float tt = fmaf(ajv, eWr[hh], base_h[hh] + (&ad.x)[jj]);
                    tt = fmaxf(tt, 0.2f * tt);
                    const float ee = ajv > 0.f ? __builtin_amdgcn_exp2f(tt) : 0.f;
                    (&dsumv[hh].x)[jj] += ee;
                    (jj == 0 ? e0 : jj == 1 ? e1 : jj == 2 ? e2 : e3) = ee;
                }
                union { fp16x2 h2[2]; f16x4 h4; } u;
                u.h2[0] = __builtin_amdgcn_cvt_pkrtz(e0, e1);
                u.h2[1] = __builtin_amdgcn_cvt_pkrtz(e2, e3);
                const uint2 hu = (ks == 0) ? make_uint2(hA.x, hA.y)
                               : (ks == 1) ? make_uint2(hA.z, hA.w)
                               : (ks == 2) ? make_uint2(hB.x, hB.y)
                                           : make_uint2(hB.z, hB.w);
                acc[hh] = mfma8f16(u.h4, u2f(hu), acc[hh]);
            }
        }
        __builtin_amdgcn_s_setprio(0);
    }

    // ---- epilogue: phased cross-wave reduce (16 waves -> 4-wave red region) ----
    __syncthreads();
#pragma unroll
    for (int hh = 0; hh < 3; ++hh) {
        const float ds = (dsumv[hh].x + dsumv[hh].y) + (dsumv[hh].z + dsumv[hh].w);
        const float dtot = ds + __shfl_xor(ds, 32);
        if (g == 0) dsum_s[(w * 3 + hh) * 32 + il] = dtot;
    }
    if (w < 4) {
#pragma unroll
        for (int hh = 0; hh < 3; ++hh)
#pragma unroll
            for (int reg = 0; reg < 16; ++reg)
                red[((w * 3 + hh) * 16 + reg) * 64 + l] = acc[hh][reg];
    }
    __syncthreads();
    if (w >= 4 && w < 8) {
#pragma unroll
        for (int hh = 0; hh < 3; ++hh)
#pragma unroll
            for (int reg = 0; reg < 16; ++reg)
                red[(((w - 4) * 3 + hh) * 16 + reg) * 64 + l] += acc[hh][reg];
    }
    __syncthreads();
    if (w >= 8 && w < 12) {
#pragma unroll
        for (int hh = 0; hh < 3; ++hh)
#pragma unroll
            for (int reg = 0; reg < 16; ++reg)
                red[(((w - 8) * 3 + hh) * 16 + reg) * 64 + l] += acc[hh][reg];
    }
    __syncthreads();
    if (w >= 12) {
#pragma unroll
        for (int hh = 0; hh < 3; ++hh)
#pragma unroll
            for (int reg = 0; reg < 16; ++reg)
                red[(((w - 12) * 3 + hh) * 16 + reg) * 64 + l] += acc[hh][reg];
    }
    __syncthreads();

    {
        const int reg = w;
        const int row_off = (reg & 3) + 8 * (reg >> 2) + 4 * g;
        const int row = i0 + row_off;
#pragma unroll
        for (int hh = 0; hh < 3; ++hh) {
            float v = 0.f, d = 0.f;
#pragma unroll
            for (int p = 0; p < 4; ++p)
                v += red[((p * 3 + hh) * 16 + reg) * 64 + l];
#pragma unroll
            for (int ww = 0; ww < 16; ++ww)
                d += dsum_s[(ww * 3 + hh) * 32 + row_off];
            const float inv = __builtin_amdgcn_rcpf(d);
            const int col = (h0 + hh) * 32 + il;
            hsum[(size_t)row * CALL + col] = (_Float16)(v * inv + res[(size_t)row * CALL + col]);
        }
    }
}

extern "C" void kernel_launch(void* const* d_in, const int* in_sizes, int n_in,
                              void* d_out, int out_size, void* d_ws, size_t ws_size,
                              hipStream_t stream)
{
    const float* x        = (const float*)d_in[0];
    const float* adj      = (const float*)d_in[1];
    const float* W        = (const float*)d_in[2];
    const float* attn_src = (const float*)d_in[3];
    const float* attn_dst = (const float*)d_in[4];
    const float* edge_W   = (const float*)d_in[5];
    const float* edge_b   = (const float*)d_in[6];
    const float* res_W    = (const float*)d_in[7];
    const float* res_b    = (const float*)d_in[8];
    const float* fus_W    = (const float*)d_in[9];
    const float* fus_b    = (const float*)d_in[10];
    float* out = (float*)d_out;

    char* ws = (char*)d_ws;
    size_t off = 0;
    auto alloc = [&](size_t bytes) { void* p = ws + off; off = (off + bytes + 255) & ~(size_t)255; return p; };
    _Float16* hT    = (_Float16*)alloc((size_t)CALL * NN * 2);
    float*    res   = (float*)alloc((size_t)NN * CALL * 4);
    float*    asrc  = (float*)alloc((size_t)NN * NH * 4);
    float*    adstT = (float*)alloc((size_t)NH * NN * 4);
    _Float16* hsum  = (_Float16*)alloc((size_t)NN * CALL * 2);
    (void)ws_size;

    gemm01<<<dim3(32, 6, 2), dim3(512), 0, stream>>>(x, W, res_W, res_b, attn_src, attn_dst, hT, res, asrc, adstT);
    attn17<<<256, dim3(1024), 0, stream>>>(adj, hT, asrc, adstT, edge_W, edge_b, res, hsum);
    gemm2<<<dim3(32, 6), dim3(512), 0, stream>>>(hsum, fus_W, fus_b, out);
}